// Round 5
// baseline (598.770 us; speedup 1.0000x reference)
//
#include <hip/hip_runtime.h>

// SelfAttnPool: B=32, T=4096, F=512, U=512 (fp32 in/out)
//   scores[b,t] = tanh(x[b,t,:]@W + b) @ V   (u never materialized)
//   a = softmax_T(scores); out[b,f] = sum_t a[b,t]*x[b,t,f]
//
// R9: retile for B-read reuse. R7 model: LDS pipe (~3840 cyc/SIMD/iter) is
// co-bottleneck with MFMA (3072). Changes vs R7 (and ONLY these):
//  - waves = 2 row x 4 col (64 rows x 128 cols each, acc still 128 AGPR).
//    Each B frag feeds 6 MFMAs (was 3) -> B ds_reads 32->16/wave/iter.
//  - B staged via global_load_lds DMA (no ds_writes, no staging VGPRs).
//  - same single barrier per K32 iter, staging+A loads issued full iter
//    ahead (barrier vmcnt drain free). No setprio, no manual frag dbuf
//    (R8 post-mortem: those regressed).
// Numerics: same cvt_hilo + per-acc term order (per h: hh,lh,hl; h asc).

#define XT 4096
#define XF 512
#define XU 512

typedef __attribute__((ext_vector_type(8))) short short8;
typedef __attribute__((ext_vector_type(16))) float f32x16;

__device__ inline void cvt_hilo(float x, unsigned short &h, unsigned short &l) {
  unsigned u = __builtin_bit_cast(unsigned, x);
  h = (unsigned short)(u >> 16);                       // truncated bf16 hi
  float hf = __builtin_bit_cast(float, u & 0xFFFF0000u);
  float lo = x - hf;                                   // exact residual
  l = (unsigned short)(__builtin_bit_cast(unsigned, lo) >> 16);
}

__device__ inline float tanh_fast(float z) {
  float e = __expf(2.0f * z);
  return 1.0f - 2.0f * __builtin_amdgcn_rcpf(e + 1.0f);
}

__device__ inline void load_lds_16B(const unsigned short *gsrc,
                                    unsigned short *ldst) {
  __builtin_amdgcn_global_load_lds(
      (const __attribute__((address_space(1))) unsigned int *)gsrc,
      (__attribute__((address_space(3))) unsigned int *)ldst, 16, 0, 0);
}

// ---- W pre-conversion: fp32 [512 k][512 n] -> bf16 hi/lo, fragment-ready:
// whi/wlo: [slice s(32)][chunk16B: t(16)*64 + g(2)*32 + l(32)][j(8)]
// element = W[k = s*16 + g*8 + j][n = t*32 + l]
__global__ void wconv_kernel(const float *__restrict__ W,
                             unsigned short *__restrict__ whi,
                             unsigned short *__restrict__ wlo) {
  int t2 = blockIdx.x * 256 + threadIdx.x;  // 32768 threads
  int l = t2 & 31;
  int g = (t2 >> 5) & 1;
  int t = (t2 >> 6) & 15;
  int s = t2 >> 10;
  short8 hv, lv;
#pragma unroll
  for (int j = 0; j < 8; ++j) {
    unsigned short h, lo;
    cvt_hilo(W[(size_t)(s * 16 + g * 8 + j) * XU + t * 32 + l], h, lo);
    hv[j] = (short)h;
    lv[j] = (short)lo;
  }
  size_t off = (size_t)s * 8192 + t * 512 + g * 256 + l * 8;
  *(short8 *)(whi + off) = hv;
  *(short8 *)(wlo + off) = lv;
}

#define MFMA(a, b, c) __builtin_amdgcn_mfma_f32_32x32x16_bf16(a, b, c, 0, 0, 0)

// ---- fused GEMM + tanh + (.@V) + chunk-local softmax + weighted pooling
// block: 512 thr = 8 waves; tile 128 rows x 512 cols.
// wave = (rw = wave&1, cw = wave>>1): rows rw*64..+64, cols cw*128..+128.
__global__ __launch_bounds__(512, 2)
void gemm_scores_kernel(const float *__restrict__ x,
                        const unsigned short *__restrict__ whi,
                        const unsigned short *__restrict__ wlo,
                        const float *__restrict__ bias,
                        const float *__restrict__ V,
                        float *__restrict__ partial,
                        float *__restrict__ pstats) {
  // B staging: per buf one K32 slice, 4 regions x 8192 ushorts:
  // region r = h*2 + hl; inside = wconv slice layout [t*512+g*256+l*8+j].
  __shared__ unsigned short Bsh[2][32768];  // 128 KB
  __shared__ float scb[512];   // [cw 4][row 128] col-slice scores
  __shared__ float sarr[128];  // chunk scores
  __shared__ float warr[128];  // chunk-local softmax weights e^{s-m}
  __shared__ float red[1536];  // pooling cross-rowgroup reduction

  const int tid = threadIdx.x;
  const int lane = tid & 63;
  const int wave = tid >> 6;
  const int rw = wave & 1;    // row half (64 rows)
  const int cw = wave >> 1;   // col quarter (128 cols)
  const int l31 = lane & 31;
  const int half = lane >> 5;
  const size_t rowbase = (size_t)blockIdx.x * 128;

  f32x16 acc[2][4];
#pragma unroll
  for (int rf = 0; rf < 2; ++rf)
#pragma unroll
    for (int cf = 0; cf < 4; ++cf)
#pragma unroll
      for (int r = 0; r < 16; ++r) acc[rf][cf][r] = 0.f;

  // A: row = rowbase + rw*64 + rf*32 + l31 ; k = j*32 + h*16 + half*8 + jj
  const float *xr0 = x + (rowbase + rw * 64 + l31) * XF + half * 8;
  const float *xr1 = xr0 + 32 * XF;
  // B frag base: region r = h*2+hl (8192 ushorts each); within region
  // t = cw*4 + cf -> ushort off t*512 + lane*8 (lane-linear, conflict-free)
  const int fbase = cw * 2048 + lane * 8;

  // staging assignment: wave -> (h = (wave>>1)>>1? ...) same as R8:
  // w2 = wave>>1 selects region (h*2+hl), wave&1 selects region half.
  const int w2 = wave >> 1;
  const unsigned short *gsrc0 = ((w2 & 1) ? wlo : whi) +
                                (size_t)(w2 >> 1) * 8192 + (wave & 1) * 4096 +
                                lane * 8;
  unsigned short *ldsW = &Bsh[0][0] + w2 * 8192 + (wave & 1) * 4096;
  unsigned short *Bsh0 = &Bsh[0][0];

  float4 xa[2][4];
  short8 ah[2][2], al[2][2];  // [rf][h]

  // ---- prologue: stage slice 0 (DMA), load A slice 0
#pragma unroll
  for (int i = 0; i < 8; ++i) load_lds_16B(gsrc0 + i * 512, ldsW + i * 512);
  xa[0][0] = *(const float4 *)(xr0);
  xa[0][1] = *(const float4 *)(xr0 + 4);
  xa[0][2] = *(const float4 *)(xr0 + 16);
  xa[0][3] = *(const float4 *)(xr0 + 20);
  xa[1][0] = *(const float4 *)(xr1);
  xa[1][1] = *(const float4 *)(xr1 + 4);
  xa[1][2] = *(const float4 *)(xr1 + 16);
  xa[1][3] = *(const float4 *)(xr1 + 20);
  __syncthreads();

#pragma unroll 1
  for (int j = 0; j < 16; ++j) {
    const unsigned short *bsC = Bsh0 + (j & 1) * 32768;

    // convert A(j) (loaded last iter; drained at barrier)
#pragma unroll
    for (int rf = 0; rf < 2; ++rf) {
#pragma unroll
      for (int h = 0; h < 2; ++h) {
        float v[8] = {xa[rf][h * 2].x, xa[rf][h * 2].y,
                      xa[rf][h * 2].z, xa[rf][h * 2].w,
                      xa[rf][h * 2 + 1].x, xa[rf][h * 2 + 1].y,
                      xa[rf][h * 2 + 1].z, xa[rf][h * 2 + 1].w};
#pragma unroll
        for (int jj = 0; jj < 8; ++jj) {
          unsigned short hh, ll;
          cvt_hilo(v[jj], hh, ll);
          ah[rf][h][jj] = (short)hh;
          al[rf][h][jj] = (short)ll;
        }
      }
    }

    // issue next-iter staging DMA + A loads (land during this iter's MFMAs)
    if (j < 15) {
      const unsigned short *gs = gsrc0 + (size_t)(j + 1) * 16384;
      unsigned short *ls = ldsW + ((j + 1) & 1) * 32768;
#pragma unroll
      for (int i = 0; i < 8; ++i) load_lds_16B(gs + i * 512, ls + i * 512);
      const float *p0 = xr0 + (j + 1) * 32;
      const float *p1 = xr1 + (j + 1) * 32;
      xa[0][0] = *(const float4 *)(p0);
      xa[0][1] = *(const float4 *)(p0 + 4);
      xa[0][2] = *(const float4 *)(p0 + 16);
      xa[0][3] = *(const float4 *)(p0 + 20);
      xa[1][0] = *(const float4 *)(p1);
      xa[1][1] = *(const float4 *)(p1 + 4);
      xa[1][2] = *(const float4 *)(p1 + 16);
      xa[1][3] = *(const float4 *)(p1 + 20);
    }

    // compute: per (h, cf) read bh/bl once, feed 6 MFMAs (2 rf x 3 terms)
#pragma unroll
    for (int h = 0; h < 2; ++h) {
      const unsigned short *bb = bsC + h * 16384 + fbase;
#pragma unroll
      for (int cf = 0; cf < 4; ++cf) {
        short8 bh = *(const short8 *)(bb + cf * 512);
        short8 bl = *(const short8 *)(bb + 8192 + cf * 512);
        acc[0][cf] = MFMA(ah[0][h], bh, acc[0][cf]);
        acc[0][cf] = MFMA(al[0][h], bh, acc[0][cf]);
        acc[0][cf] = MFMA(ah[0][h], bl, acc[0][cf]);
        acc[1][cf] = MFMA(ah[1][h], bh, acc[1][cf]);
        acc[1][cf] = MFMA(al[1][h], bh, acc[1][cf]);
        acc[1][cf] = MFMA(ah[1][h], bl, acc[1][cf]);
      }
    }

    __syncthreads();
  }

  // ---- score epilogue: sc[rf][r] = sum over this wave's 128 cols
  // C/D 32x32: col n = cw*128 + cf*32 + l31
  // row = rw*64 + rf*32 + (r&3)+8*(r>>2)+4*half
  float sc[2][16];
#pragma unroll
  for (int rf = 0; rf < 2; ++rf)
#pragma unroll
    for (int r = 0; r < 16; ++r) sc[rf][r] = 0.f;
#pragma unroll
  for (int cf = 0; cf < 4; ++cf) {
    int n = cw * 128 + cf * 32 + l31;
    float vv = V[n];
    float bb = bias[n];
#pragma unroll
    for (int rf = 0; rf < 2; ++rf)
#pragma unroll
      for (int r = 0; r < 16; ++r)
        sc[rf][r] += tanh_fast(acc[rf][cf][r] + bb) * vv;
  }
#pragma unroll
  for (int m = 1; m <= 16; m <<= 1) {
#pragma unroll
    for (int rf = 0; rf < 2; ++rf)
#pragma unroll
      for (int r = 0; r < 16; ++r)
        sc[rf][r] += __shfl_xor(sc[rf][r], m, 64);
  }
  if (l31 == 0) {
#pragma unroll
    for (int rf = 0; rf < 2; ++rf)
#pragma unroll
      for (int r = 0; r < 16; ++r) {
        int row = rw * 64 + rf * 32 + (r & 3) + 8 * (r >> 2) + 4 * half;
        scb[cw * 128 + row] = sc[rf][r];
      }
  }
  __syncthreads();

  // ---- chunk-local softmax over 128 rows
  if (tid < 128)
    sarr[tid] = (scb[tid] + scb[128 + tid]) + (scb[256 + tid] + scb[384 + tid]);
  __syncthreads();
  float mloc = -1e30f;
#pragma unroll 8
  for (int i = 0; i < 128; ++i) mloc = fmaxf(mloc, sarr[i]);
  if (tid < 128) warr[tid] = __expf(sarr[tid] - mloc);
  __syncthreads();

  // l_c = sum warr : 64-lane shuffle reduce
  float lsum = 0.f;
  if (tid < 64) {
    lsum = warr[tid] + warr[tid + 64];
#pragma unroll
    for (int m = 1; m < 64; m <<= 1) lsum += __shfl_xor(lsum, m, 64);
  }

  // ---- weighted pooling over own (L2-hot) tile: 4 row-groups x 128 col4s
  const int rg = tid >> 7;   // 0..3 -> rows rg*32..+32
  const int c4 = tid & 127;  // float4 column
  const float *xp = x + rowbase * XF;
  float4 pa = {0.f, 0.f, 0.f, 0.f};
#pragma unroll 8
  for (int i = 0; i < 32; ++i) {
    int r = rg * 32 + i;
    float4 v = *(const float4 *)(xp + (size_t)r * XF + c4 * 4);
    float wv = warr[r];
    pa.x += wv * v.x;
    pa.y += wv * v.y;
    pa.z += wv * v.z;
    pa.w += wv * v.w;
  }
  if (rg > 0) {
    float *rp = red + (rg - 1) * 512 + c4 * 4;
    rp[0] = pa.x; rp[1] = pa.y; rp[2] = pa.z; rp[3] = pa.w;
  }
  __syncthreads();
  if (rg == 0) {
    const float *r0 = red + c4 * 4;
    float4 o;
    o.x = pa.x + r0[0] + r0[512] + r0[1024];
    o.y = pa.y + r0[1] + r0[513] + r0[1025];
    o.z = pa.z + r0[2] + r0[514] + r0[1026];
    o.w = pa.w + r0[3] + r0[515] + r0[1027];
    *(float4 *)(partial + (size_t)blockIdx.x * 512 + c4 * 4) = o;
  }
  if (tid == 0) {
    pstats[blockIdx.x * 2] = mloc;
    pstats[blockIdx.x * 2 + 1] = lsum;
  }
}

// ---- combine: out[b,f] = sum_c e^{m_c-M} partial[c][f] / (sum_c e^{m_c-M} l_c)
__global__ __launch_bounds__(512)
void combine_kernel(const float *__restrict__ partial,
                    const float *__restrict__ pstats,
                    float *__restrict__ out) {
  int b = blockIdx.x;
  int f = threadIdx.x;
  __shared__ float ml[32], ll[32];
  if (f < 32) {
    ml[f] = pstats[(b * 32 + f) * 2];
    ll[f] = pstats[(b * 32 + f) * 2 + 1];
  }
  __syncthreads();
  float M = -1e30f;
#pragma unroll
  for (int c = 0; c < 32; ++c) M = fmaxf(M, ml[c]);
  float L = 0.f;
#pragma unroll
  for (int c = 0; c < 32; ++c) L += __expf(ml[c] - M) * ll[c];
  float acc = 0.f;
#pragma unroll
  for (int c = 0; c < 32; ++c)
    acc += __expf(ml[c] - M) * partial[(size_t)(b * 32 + c) * 512 + f];
  out[b * XF + f] = acc / L;
}

extern "C" void kernel_launch(void *const *d_in, const int *in_sizes, int n_in,
                              void *d_out, int out_size, void *d_ws,
                              size_t ws_size, hipStream_t stream) {
  const float *x = (const float *)d_in[0];
  const float *W = (const float *)d_in[1];
  const float *bias = (const float *)d_in[2];
  const float *V = (const float *)d_in[3];
  float *out = (float *)d_out;

  // workspace: whi 512KB | wlo 512KB | partial 2MB | pstats 8KB
  unsigned short *whi = (unsigned short *)d_ws;
  unsigned short *wlo = whi + 262144;
  float *partial = (float *)((char *)d_ws + 1048576);
  float *pstats = (float *)((char *)d_ws + 1048576 + 2097152);

  wconv_kernel<<<128, 256, 0, stream>>>(W, whi, wlo);
  gemm_scores_kernel<<<1024, 512, 0, stream>>>(x, whi, wlo, bias, V, partial,
                                               pstats);
  combine_kernel<<<32, 512, 0, stream>>>(partial, pstats, out);
}